// Round 7
// baseline (286.036 us; speedup 1.0000x reference)
//
#include <hip/hip_runtime.h>
#include <hip/hip_bf16.h>

#define K30REV 4.77464829275686f   /* 30/(2*pi) */
#define ASTRIDE 264                /* A-tile row stride: 256 + 8 pad; 33 x 8B (odd) ->
                                      b64 column access across rows is bank-conflict-free */

typedef __attribute__((ext_vector_type(4))) float f32x4;
typedef __attribute__((ext_vector_type(8))) short s16x8;
typedef __attribute__((ext_vector_type(4))) short s16x4;

__device__ __forceinline__ short f2bf(float f) {
    union { float f; unsigned u; } a; a.f = f;
    unsigned r = a.u + 0x7fffu + ((a.u >> 16) & 1u);
    return (short)(r >> 16);
}

__device__ __forceinline__ unsigned pk2(float a, float b) {
    union { __hip_bfloat162 h; unsigned u; } cv;
    cv.h = __float22bfloat162_rn(make_float2(a, b));
    return cv.u;
}

// two ds_read_b64 -> one MFMA fragment (16B-misalignable, conflict-free at 264B stride)
__device__ __forceinline__ s16x8 lds_frag(const char* p) {
    s16x4 lo = *(const s16x4*)p;
    s16x4 hi = *(const s16x4*)(p + 8);
    return __builtin_shufflevector(lo, hi, 0, 1, 2, 3, 4, 5, 6, 7);
}

// ---------- merged prep ----------
// [0,524288): radial tables tab[n][{cosA,sinA,cosB,sinB}][128]
// [+65536): Wswz — hidden weights in MFMA-fragment-contiguous order:
//           wswz[layer*16384 + ntg*2048 + ks*512 + lane*8 + j]
//             = W_layer[(ntg*16 + (lane&15))*128 + ks*32 + (lane>>4)*8 + j]
// [+2048): W4 zero-padded [16][128] ; [+512): brev = bias*K30REV ; [+20480): pt tables
__global__ void k_prep(const float* __restrict__ ktraj,
                       const float* __restrict__ W0, const float* __restrict__ W1,
                       const float* __restrict__ W2, const float* __restrict__ W3,
                       const float* __restrict__ W4,
                       const float* __restrict__ b0, const float* __restrict__ b1,
                       const float* __restrict__ b2, const float* __restrict__ b3,
                       const float* __restrict__ Bmat,
                       float* __restrict__ tab, short* __restrict__ wswz,
                       short* __restrict__ w4pad, float* __restrict__ brev,
                       float* __restrict__ ptx, float* __restrict__ pty,
                       float* __restrict__ ptz) {
    int i = blockIdx.x * 256 + threadIdx.x;
    if (i < 524288) {
        int n = i >> 8, s = i & 255;
        if (s < 128) {
            float a = ktraj[n] * (float)s;
            tab[n * 512 + s]       = __cosf(a);
            tab[n * 512 + 128 + s] = __sinf(a);
        } else {
            int y = s - 128;
            float a = ktraj[2048 + n] * (float)y;
            tab[n * 512 + 256 + y] = __cosf(a);
            tab[n * 512 + 384 + y] = __sinf(a);
        }
        return;
    }
    i -= 524288;
    if (i < 65536) {
        int layer = i >> 14, q = i & 16383;
        int ntg = q >> 11, ks = (q >> 9) & 3, rem = q & 511;
        int ln = rem >> 3, j = rem & 7;
        int row = ntg * 16 + (ln & 15);
        int col = ks * 32 + (ln >> 4) * 8 + j;
        const float* src = (layer == 0) ? W0 : (layer == 1) ? W1 : (layer == 2) ? W2 : W3;
        wswz[i] = f2bf(src[row * 128 + col]);
        return;
    }
    i -= 65536;
    if (i < 2048) {
        int row = i >> 7, col = i & 127;
        w4pad[i] = f2bf(row == 0 ? W4[col] : 0.0f);
        return;
    }
    i -= 2048;
    if (i < 512) {
        int l = i >> 7, col = i & 127;
        const float* src = (l == 0) ? b0 : (l == 1) ? b1 : (l == 2) ? b2 : b3;
        brev[i] = src[col] * K30REV;
        return;
    }
    i -= 512;
    if (i < 8192) {             // ptx
        int x = i >> 6, e = i & 63;
        ptx[i] = ((x + 0.5f) * (1.0f / 128.0f)) * Bmat[e * 3 + 0];
        return;
    }
    i -= 8192;
    if (i < 8192) {             // pty
        int y = i >> 6, e = i & 63;
        pty[i] = ((y + 0.5f) * (1.0f / 128.0f)) * Bmat[e * 3 + 1];
        return;
    }
    i -= 8192;
    if (i < 4096) {             // ptz
        int z = i >> 6, e = i & 63;
        ptz[i] = ((z + 0.5f) * (1.0f / 64.0f)) * Bmat[e * 3 + 2];
    }
}

// ---------- kernel 1: fused encode + SIREN + (vol - image) ----------
// 256 thr = 4 waves as 2(row: 64 rows)x2(col: 64 neurons) over a 128-row tile.
// 33.8 KB LDS -> 4 independent blocks/CU. af = fragment-contiguous Wswz (1 KB
// coalesced per load). A-tile rows at 264 B stride: every LDS op is b64 and
// bank-conflict-free (pair index (l15 + 2*l4 + c) mod 16 -> 4 lanes/pair).
// Swapped MFMA: mfma(af=W, bf=A rows) -> lane: A-row=l15, neuron=l4*4+jj.
__launch_bounds__(256, 4)
__global__ void k_siren(const float* __restrict__ ptx, const float* __restrict__ pty,
                        const float* __restrict__ ptz,
                        const float* __restrict__ brev,
                        const float* __restrict__ b4,
                        const short* __restrict__ wswz,
                        const short* __restrict__ w4pad,
                        const float* __restrict__ image,
                        float* __restrict__ d_nat) {
    __shared__ alignas(16) char Abuf[128 * ASTRIDE];   // 33792 B
    const int tid  = threadIdx.x;
    const int lane = tid & 63;
    const int w    = tid >> 6;
    const int wr   = w >> 1;        // 0..1: rows wr*64 .. +63
    const int wc   = w & 1;         // 0..1: neurons wc*64 .. +63
    const int l15  = lane & 15;
    const int l4   = lane >> 4;
    const int nbase = blockIdx.x * 128;
    const f32x4 zero4 = (f32x4){0.f, 0.f, 0.f, 0.f};

    // ---- encode: 2 threads per row, 32 freqs each; p = ptx[x]+pty[y]+ptz[z] ----
    {
        int row = tid >> 1, h = tid & 1;
        int n = nbase + row;
        int x = n >> 13, y = (n >> 6) & 127, z = n & 63;
        const float* pxr = ptx + x * 64 + h * 32;
        const float* pyr = pty + y * 64 + h * 32;
        const float* pzr = ptz + z * 64 + h * 32;
        char* rowp = Abuf + row * ASTRIDE + h * 64;
        #pragma unroll
        for (int eb = 0; eb < 32; eb += 8) {
            f32x4 xa = *(const f32x4*)(pxr + eb),     xb = *(const f32x4*)(pxr + eb + 4);
            f32x4 ya = *(const f32x4*)(pyr + eb),     yb = *(const f32x4*)(pyr + eb + 4);
            f32x4 za = *(const f32x4*)(pzr + eb),     zb = *(const f32x4*)(pzr + eb + 4);
            float p[8];
            #pragma unroll
            for (int j = 0; j < 4; j++) {
                p[j]     = xa[j] + ya[j] + za[j];
                p[4 + j] = xb[j] + yb[j] + zb[j];
            }
            unsigned vs[4], vc[4];
            #pragma unroll
            for (int j = 0; j < 4; j++) {
                vs[j] = pk2(__builtin_amdgcn_sinf(p[2 * j]), __builtin_amdgcn_sinf(p[2 * j + 1]));
                vc[j] = pk2(__builtin_amdgcn_cosf(p[2 * j]), __builtin_amdgcn_cosf(p[2 * j + 1]));
            }
            *(uint2*)(rowp + 2 * eb)           = make_uint2(vs[0], vs[1]);   // sin cols
            *(uint2*)(rowp + 2 * eb + 8)       = make_uint2(vs[2], vs[3]);
            *(uint2*)(rowp + 128 + 2 * eb)     = make_uint2(vc[0], vc[1]);   // cos cols
            *(uint2*)(rowp + 128 + 2 * eb + 8) = make_uint2(vc[2], vc[3]);
        }
    }

    // ---- layer-invariant LDS addresses ----
    int rbase[4], wbase2[4];
    #pragma unroll
    for (int rt = 0; rt < 4; rt++) {
        int rowoff = (wr * 64 + rt * 16 + l15) * ASTRIDE;
        rbase[rt]  = rowoff + l4 * 16;              // + ks*64 on read
        wbase2[rt] = rowoff + wc * 128 + l4 * 8;    // + nt*32 on write
    }
    const short* Wlane = wswz + wc * 8192 + lane * 8;   // + layer*16384 + nt*2048 + ks*512

    __syncthreads();

    // ---- 4 hidden layers ----
    #pragma unroll 1
    for (int layer = 0; layer < 4; layer++) {
        const short* W = Wlane + layer * 16384;
        f32x4 acc[4][4];

        // ks = 0: accumulator initialized through the MFMA C operand (no movs)
        {
            s16x8 bfr[4];
            #pragma unroll
            for (int rt = 0; rt < 4; rt++)
                bfr[rt] = lds_frag(Abuf + rbase[rt]);
            #pragma unroll
            for (int nt = 0; nt < 4; nt++) {
                s16x8 af = *(const s16x8*)(W + nt * 2048);
                #pragma unroll
                for (int rt = 0; rt < 4; rt++)
                    acc[rt][nt] = __builtin_amdgcn_mfma_f32_16x16x32_bf16(af, bfr[rt], zero4, 0, 0, 0);
            }
        }
        #pragma unroll
        for (int ks = 1; ks < 4; ks++) {
            s16x8 bfr[4];
            #pragma unroll
            for (int rt = 0; rt < 4; rt++)
                bfr[rt] = lds_frag(Abuf + rbase[rt] + ks * 64);
            #pragma unroll
            for (int nt = 0; nt < 4; nt++) {
                s16x8 af = *(const s16x8*)(W + nt * 2048 + ks * 512);
                #pragma unroll
                for (int rt = 0; rt < 4; rt++)
                    acc[rt][nt] = __builtin_amdgcn_mfma_f32_16x16x32_bf16(af, bfr[rt], acc[rt][nt], 0, 0, 0);
            }
        }
        __syncthreads();   // all reads done before overwrite
        #pragma unroll
        for (int nt = 0; nt < 4; nt++) {
            f32x4 bb = *(const f32x4*)(brev + layer * 128 + wc * 64 + nt * 16 + l4 * 4);
            #pragma unroll
            for (int rt = 0; rt < 4; rt++) {
                float s0 = __builtin_amdgcn_sinf(fmaf(acc[rt][nt][0], K30REV, bb[0]));
                float s1 = __builtin_amdgcn_sinf(fmaf(acc[rt][nt][1], K30REV, bb[1]));
                float s2 = __builtin_amdgcn_sinf(fmaf(acc[rt][nt][2], K30REV, bb[2]));
                float s3 = __builtin_amdgcn_sinf(fmaf(acc[rt][nt][3], K30REV, bb[3]));
                *(uint2*)(Abuf + wbase2[rt] + nt * 32) = make_uint2(pk2(s0, s1), pk2(s2, s3));
            }
        }
        __syncthreads();   // writes visible before next layer reads
    }

    // ---- final layer (unswapped): af=A rows, bf=W4 padded; 32 rows per wave ----
    {
        const short* W4p = w4pad + l15 * 128 + l4 * 8;
        f32x4 a4[2];
        a4[0] = zero4;
        a4[1] = zero4;
        #pragma unroll
        for (int ks = 0; ks < 4; ks++) {
            s16x8 bw = *(const s16x8*)(W4p + ks * 32);
            #pragma unroll
            for (int q = 0; q < 2; q++) {
                int row = w * 32 + q * 16 + l15;
                s16x8 af = lds_frag(Abuf + row * ASTRIDE + ks * 64 + l4 * 16);
                a4[q] = __builtin_amdgcn_mfma_f32_16x16x32_bf16(af, bw, a4[q], 0, 0, 0);
            }
        }
        if (l15 == 0) {
            float b4v = b4[0];
            #pragma unroll
            for (int q = 0; q < 2; q++) {
                int n = nbase + w * 32 + q * 16 + l4 * 4;
                const f32x4 img = *(const f32x4*)(image + n);
                f32x4 dv;
                #pragma unroll
                for (int jj = 0; jj < 4; jj++) dv[jj] = a4[q][jj] + b4v - img[jj];
                *(f32x4*)(d_nat + n) = dv;
            }
        }
    }
}

// ---------- kernel 1.5: d_nat [x][y][z] fp32 -> d_proj [z][x*128+y] bf16 ----------
__global__ void k_transpose(const float* __restrict__ d_nat, short* __restrict__ d_proj) {
    __shared__ float t[128][65];
    int x = blockIdx.x;
    for (int i = threadIdx.x; i < 8192; i += 256)
        t[i >> 6][i & 63] = d_nat[x * 8192 + i];
    __syncthreads();
    for (int i = threadIdx.x; i < 8192; i += 256) {
        int z = i >> 7, y = i & 127;
        d_proj[z * 16384 + x * 128 + y] = f2bf(t[y][z]);
    }
}

// ---------- kernel 2: NUDFT GEMM (M=64 z, N=2048 k-samples, K=16384 pixels) ----------
__launch_bounds__(256, 2)
__global__ void k_project(const short* __restrict__ d_proj, const float* __restrict__ tab,
                          float* __restrict__ part) {
    __shared__ alignas(16) float lt[4 * 32 * 132];   // 67584 B; reused as reduce buffer
    const int tid  = threadIdx.x;
    const int lane = tid & 63;
    const int w    = tid >> 6;
    const int l15  = lane & 15;
    const int l4   = lane >> 4;
    const int nblk = blockIdx.x & 63;
    const int ksp  = blockIdx.x >> 6;
    const int nbase = nblk * 32;

    for (int i = tid; i < 16384; i += 256) {
        int nl = i >> 9, r = i & 511;
        int t = r >> 7, e = r & 127;
        lt[(t * 32 + nl) * 132 + e] = tab[(nbase + nl) * 512 + r];
    }
    __syncthreads();

    f32x4 ar[4][2], ai[4][2];
    #pragma unroll
    for (int rt = 0; rt < 4; rt++)
        #pragma unroll
        for (int nt = 0; nt < 2; nt++) {
            ar[rt][nt] = (f32x4){0.f, 0.f, 0.f, 0.f};
            ai[rt][nt] = (f32x4){0.f, 0.f, 0.f, 0.f};
        }

    const int p2base = ksp * 2048 + w * 512;
    #pragma unroll 1
    for (int ks = 0; ks < 16; ks++) {
        int p2c = p2base + ks * 32;
        s16x8 afr[4];
        #pragma unroll
        for (int rt = 0; rt < 4; rt++)
            afr[rt] = *(const s16x8*)(d_proj + (rt * 16 + l15) * 16384 + p2c + l4 * 8);
        int p2 = p2c + l4 * 8;
        int x = p2 >> 7, y0 = p2 & 127;
        #pragma unroll
        for (int nt = 0; nt < 2; nt++) {
            int nl = nt * 16 + l15;
            float cA = lt[nl * 132 + x];
            float sA = lt[(32 + nl) * 132 + x];
            const float* cB = &lt[(64 + nl) * 132 + y0];
            const float* sB = &lt[(96 + nl) * 132 + y0];
            s16x8 bc, bs;
            #pragma unroll
            for (int j = 0; j < 8; j++) {
                float cb = cB[j], sb = sB[j];
                bc[j] = f2bf(cA * cb - sA * sb);
                bs[j] = f2bf(sA * cb + cA * sb);
            }
            #pragma unroll
            for (int rt = 0; rt < 4; rt++) {
                ar[rt][nt] = __builtin_amdgcn_mfma_f32_16x16x32_bf16(afr[rt], bc, ar[rt][nt], 0, 0, 0);
                ai[rt][nt] = __builtin_amdgcn_mfma_f32_16x16x32_bf16(afr[rt], bs, ai[rt][nt], 0, 0, 0);
            }
        }
    }
    __syncthreads();   // tables dead; reuse lt as reduce buffer
    float* red = lt;
    #pragma unroll
    for (int rt = 0; rt < 4; rt++)
        #pragma unroll
        for (int nt = 0; nt < 2; nt++)
            #pragma unroll
            for (int jj = 0; jj < 4; jj++) {
                int z = rt * 16 + l4 * 4 + jj;
                int q = nt * 16 + l15;
                red[(w * 64 + z) * 64 + q * 2 + 0] = ar[rt][nt][jj];
                red[(w * 64 + z) * 64 + q * 2 + 1] = ai[rt][nt][jj];
            }
    __syncthreads();
    for (int i = tid; i < 4096; i += 256) {
        int z = i >> 6, q = i & 63;
        float s = red[z * 64 + q] + red[4096 + z * 64 + q] + red[8192 + z * 64 + q] + red[12288 + z * 64 + q];
        part[((ksp * 64 + z) * 2048 + nbase + (q >> 1)) * 2 + (q & 1)] = s;
    }
}

// ---------- kernel 3: sum K-split partials, square, reduce to loss ----------
__global__ void k_loss(const float* __restrict__ part, float* __restrict__ out) {
    int g = blockIdx.x * 256 + threadIdx.x;   // 131072 (z,n) pairs
    int z = g >> 11, n = g & 2047;
    float r = 0.f, im = 0.f;
    #pragma unroll
    for (int ksp = 0; ksp < 8; ksp++) {
        const float2 v = *(const float2*)(part + ((ksp * 64 + z) * 2048 + n) * 2);
        r += v.x; im += v.y;
    }
    float val = r * r + im * im;
    #pragma unroll
    for (int o = 32; o > 0; o >>= 1) val += __shfl_xor(val, o);
    __shared__ float sred[4];
    if ((threadIdx.x & 63) == 0) sred[threadIdx.x >> 6] = val;
    __syncthreads();
    if (threadIdx.x == 0)
        atomicAdd(out, (sred[0] + sred[1] + sred[2] + sred[3]) * (0.5f / 131072.0f));
}

extern "C" void kernel_launch(void* const* d_in, const int* in_sizes, int n_in,
                              void* d_out, int out_size, void* d_ws, size_t ws_size,
                              hipStream_t stream) {
    const float* Bmat  = (const float*)d_in[1];
    const float* W0    = (const float*)d_in[2];
    const float* b0    = (const float*)d_in[3];
    const float* W1    = (const float*)d_in[4];
    const float* b1    = (const float*)d_in[5];
    const float* W2    = (const float*)d_in[6];
    const float* b2    = (const float*)d_in[7];
    const float* W3    = (const float*)d_in[8];
    const float* b3    = (const float*)d_in[9];
    const float* W4    = (const float*)d_in[10];
    const float* b4    = (const float*)d_in[11];
    const float* image = (const float*)d_in[12];
    const float* ktraj = (const float*)d_in[13];

    char* ws = (char*)d_ws;
    short* w4pad  = (short*)(ws);                  // 4 KB
    float* brev   = (float*)(ws + (8u << 10));     // 2 KB
    float* ptx    = (float*)(ws + (64u << 10));    // 32 KB
    float* pty    = (float*)(ws + (96u << 10));    // 32 KB
    float* ptz    = (float*)(ws + (128u << 10));   // 16 KB
    short* wswz   = (short*)(ws + (160u << 10));   // 128 KB (fragment-contiguous W0..W3)
    float* tab    = (float*)(ws + (1u << 20));     // 4 MB
    float* d_nat  = (float*)(ws + (5u << 20));     // 4 MB
    short* d_proj = (short*)(ws + (9u << 20));     // 2 MB
    float* part   = (float*)(ws + (11u << 20));    // 8 MB
    float* outf   = (float*)d_out;

    hipLaunchKernelGGL(k_prep,      dim3(2394), dim3(256), 0, stream,
                       ktraj, W0, W1, W2, W3, W4, b0, b1, b2, b3, Bmat,
                       tab, wswz, w4pad, brev, ptx, pty, ptz);
    hipLaunchKernelGGL(k_siren,     dim3(8192), dim3(256), 0, stream,
                       ptx, pty, ptz, brev, b4, wswz, w4pad, image, d_nat);
    hipLaunchKernelGGL(k_transpose, dim3(128),  dim3(256), 0, stream, d_nat, d_proj);
    hipLaunchKernelGGL(k_project,   dim3(512),  dim3(256), 0, stream, d_proj, tab, part);
    hipMemsetAsync(d_out, 0, sizeof(float), stream);
    hipLaunchKernelGGL(k_loss,      dim3(512),  dim3(256), 0, stream, part, outf);
}

// Round 8
// 248.388 us; speedup vs baseline: 1.1516x; 1.1516x over previous
//
#include <hip/hip_runtime.h>
#include <hip/hip_bf16.h>

#define K30REV 4.77464829275686f   /* 30/(2*pi) */

typedef __attribute__((ext_vector_type(4))) float f32x4;
typedef __attribute__((ext_vector_type(8))) short s16x8;

__device__ __forceinline__ short f2bf(float f) {
    union { float f; unsigned u; } a; a.f = f;
    unsigned r = a.u + 0x7fffu + ((a.u >> 16) & 1u);
    return (short)(r >> 16);
}

__device__ __forceinline__ unsigned pk2(float a, float b) {
    union { __hip_bfloat162 h; unsigned u; } cv;
    cv.h = __float22bfloat162_rn(make_float2(a, b));
    return cv.u;
}

// ---------- merged prep ----------
// [0,524288): radial tables tab[n][{cosA,sinA,cosB,sinB}][128]
// [+65536): Wswz — hidden weights in MFMA-fragment-contiguous order:
//           wswz[layer*16384 + ntg*2048 + ks*512 + lane*8 + j]
//             = W_layer[(ntg*16 + (lane&15))*128 + ks*32 + (lane>>4)*8 + j]
// [+2048): W4 zero-padded [16][128] ; [+512): brev = bias*K30REV ; [+20480): pt tables
__global__ void k_prep(const float* __restrict__ ktraj,
                       const float* __restrict__ W0, const float* __restrict__ W1,
                       const float* __restrict__ W2, const float* __restrict__ W3,
                       const float* __restrict__ W4,
                       const float* __restrict__ b0, const float* __restrict__ b1,
                       const float* __restrict__ b2, const float* __restrict__ b3,
                       const float* __restrict__ Bmat,
                       float* __restrict__ tab, short* __restrict__ wswz,
                       short* __restrict__ w4pad, float* __restrict__ brev,
                       float* __restrict__ ptx, float* __restrict__ pty,
                       float* __restrict__ ptz) {
    int i = blockIdx.x * 256 + threadIdx.x;
    if (i < 524288) {
        int n = i >> 8, s = i & 255;
        if (s < 128) {
            float a = ktraj[n] * (float)s;
            tab[n * 512 + s]       = __cosf(a);
            tab[n * 512 + 128 + s] = __sinf(a);
        } else {
            int y = s - 128;
            float a = ktraj[2048 + n] * (float)y;
            tab[n * 512 + 256 + y] = __cosf(a);
            tab[n * 512 + 384 + y] = __sinf(a);
        }
        return;
    }
    i -= 524288;
    if (i < 65536) {
        int layer = i >> 14, q = i & 16383;
        int ntg = q >> 11, ks = (q >> 9) & 3, rem = q & 511;
        int ln = rem >> 3, j = rem & 7;
        int row = ntg * 16 + (ln & 15);
        int col = ks * 32 + (ln >> 4) * 8 + j;
        const float* src = (layer == 0) ? W0 : (layer == 1) ? W1 : (layer == 2) ? W2 : W3;
        wswz[i] = f2bf(src[row * 128 + col]);
        return;
    }
    i -= 65536;
    if (i < 2048) {
        int row = i >> 7, col = i & 127;
        w4pad[i] = f2bf(row == 0 ? W4[col] : 0.0f);
        return;
    }
    i -= 2048;
    if (i < 512) {
        int l = i >> 7, col = i & 127;
        const float* src = (l == 0) ? b0 : (l == 1) ? b1 : (l == 2) ? b2 : b3;
        brev[i] = src[col] * K30REV;
        return;
    }
    i -= 512;
    if (i < 8192) {             // ptx
        int x = i >> 6, e = i & 63;
        ptx[i] = ((x + 0.5f) * (1.0f / 128.0f)) * Bmat[e * 3 + 0];
        return;
    }
    i -= 8192;
    if (i < 8192) {             // pty
        int y = i >> 6, e = i & 63;
        pty[i] = ((y + 0.5f) * (1.0f / 128.0f)) * Bmat[e * 3 + 1];
        return;
    }
    i -= 8192;
    if (i < 4096) {             // ptz
        int z = i >> 6, e = i & 63;
        ptz[i] = ((z + 0.5f) * (1.0f / 64.0f)) * Bmat[e * 3 + 2];
    }
}

// ---------- kernel 1: fused encode + SIREN + (vol - image) ----------
// 256 thr = 4 waves as 2(row: 64 rows)x2(col: 64 neurons) over a 128-row tile.
// A-tile in LDS stored in MFMA-FRAGMENT order:
//   Abuf[(rg*4 + ks)*1024 + lane*16 + j*2] = A[rg*16 + (lane&15)][ks*32 + (lane>>4)*8 + j]
// -> bf load = ONE ds_read_b128 at base + lane*16 (linear, zero conflicts, no
//    register re-forming — fixes R7's scratch-spill), exactly 32 KB -> 4 blocks/CU.
// Activation writeback: 4 consecutive k of one row = one ds_write_b64.
// af = fragment-contiguous Wswz (1 KB linear per load).
__launch_bounds__(256, 4)
__global__ void k_siren(const float* __restrict__ ptx, const float* __restrict__ pty,
                        const float* __restrict__ ptz,
                        const float* __restrict__ brev,
                        const float* __restrict__ b4,
                        const short* __restrict__ wswz,
                        const short* __restrict__ w4pad,
                        const float* __restrict__ image,
                        float* __restrict__ d_nat) {
    __shared__ alignas(16) char Abuf[32768];   // [8 rg][4 ks][64 lanes][16 B]
    const int tid  = threadIdx.x;
    const int lane = tid & 63;
    const int w    = tid >> 6;
    const int wr   = w >> 1;        // 0..1: rows wr*64 .. +63
    const int wc   = w & 1;         // 0..1: neurons wc*64 .. +63
    const int l15  = lane & 15;
    const int l4   = lane >> 4;
    const int nbase = blockIdx.x * 128;
    const f32x4 zero4 = (f32x4){0.f, 0.f, 0.f, 0.f};

    // ---- encode: 2 threads per row, 32 freqs each; p = ptx[x]+pty[y]+ptz[z] ----
    // feature k-index: sin_e -> k=e (ks=h), cos_e -> k=64+e (ks=2+h); e in [32h,32h+32)
    {
        int row = tid >> 1, h = tid & 1;
        int n = nbase + row;
        int x = n >> 13, y = (n >> 6) & 127, z = n & 63;
        const float* pxr = ptx + x * 64 + h * 32;
        const float* pyr = pty + y * 64 + h * 32;
        const float* pzr = ptz + z * 64 + h * 32;
        int rg = row >> 4, r15 = row & 15;
        char* sbase = Abuf + (rg * 4 + h) * 1024;       // sin subtile
        char* cbase = Abuf + (rg * 4 + 2 + h) * 1024;   // cos subtile
        #pragma unroll
        for (int eb = 0; eb < 32; eb += 8) {
            f32x4 xa = *(const f32x4*)(pxr + eb),     xb = *(const f32x4*)(pxr + eb + 4);
            f32x4 ya = *(const f32x4*)(pyr + eb),     yb = *(const f32x4*)(pyr + eb + 4);
            f32x4 za = *(const f32x4*)(pzr + eb),     zb = *(const f32x4*)(pzr + eb + 4);
            float p[8];
            #pragma unroll
            for (int j = 0; j < 4; j++) {
                p[j]     = xa[j] + ya[j] + za[j];
                p[4 + j] = xb[j] + yb[j] + zb[j];
            }
            unsigned vs[4], vc[4];
            #pragma unroll
            for (int j = 0; j < 4; j++) {
                vs[j] = pk2(__builtin_amdgcn_sinf(p[2 * j]), __builtin_amdgcn_sinf(p[2 * j + 1]));
                vc[j] = pk2(__builtin_amdgcn_cosf(p[2 * j]), __builtin_amdgcn_cosf(p[2 * j + 1]));
            }
            int lanep = ((eb >> 3) * 16 + r15) * 16;    // fragment slot for these 8 k's
            *(uint4*)(sbase + lanep) = *(uint4*)vs;
            *(uint4*)(cbase + lanep) = *(uint4*)vc;
        }
    }

    // ---- layer-invariant addresses ----
    // read:  Abuf + wr*16384 + rt*4096 + ks*1024 + lane*16
    // write: Abuf + wr*16384 + rt*4096 + woff[nt]  (one b64: 4 consecutive k of row l15)
    const int rdbase = wr * 16384 + lane * 16;
    int woff[4];
    #pragma unroll
    for (int nt = 0; nt < 4; nt++) {
        int n0 = wc * 64 + nt * 16 + l4 * 4;
        woff[nt] = (n0 >> 5) * 1024 + (((n0 >> 3) & 3) * 16 + l15) * 16 + (n0 & 4) * 2;
    }
    const short* Wlane = wswz + wc * 8192 + lane * 8;   // + layer*16384 + nt*2048 + ks*512

    __syncthreads();

    // ---- 4 hidden layers ----
    #pragma unroll 1
    for (int layer = 0; layer < 4; layer++) {
        const short* W = Wlane + layer * 16384;
        f32x4 acc[4][4];

        // ks = 0: accumulator initialized through the MFMA C operand
        {
            s16x8 bfr[4];
            #pragma unroll
            for (int rt = 0; rt < 4; rt++)
                bfr[rt] = *(const s16x8*)(Abuf + rdbase + rt * 4096);
            #pragma unroll
            for (int nt = 0; nt < 4; nt++) {
                s16x8 af = *(const s16x8*)(W + nt * 2048);
                #pragma unroll
                for (int rt = 0; rt < 4; rt++)
                    acc[rt][nt] = __builtin_amdgcn_mfma_f32_16x16x32_bf16(af, bfr[rt], zero4, 0, 0, 0);
            }
        }
        #pragma unroll
        for (int ks = 1; ks < 4; ks++) {
            s16x8 bfr[4];
            #pragma unroll
            for (int rt = 0; rt < 4; rt++)
                bfr[rt] = *(const s16x8*)(Abuf + rdbase + rt * 4096 + ks * 1024);
            #pragma unroll
            for (int nt = 0; nt < 4; nt++) {
                s16x8 af = *(const s16x8*)(W + nt * 2048 + ks * 512);
                #pragma unroll
                for (int rt = 0; rt < 4; rt++)
                    acc[rt][nt] = __builtin_amdgcn_mfma_f32_16x16x32_bf16(af, bfr[rt], acc[rt][nt], 0, 0, 0);
            }
        }
        __syncthreads();   // all reads done before overwrite
        #pragma unroll
        for (int nt = 0; nt < 4; nt++) {
            f32x4 bb = *(const f32x4*)(brev + layer * 128 + wc * 64 + nt * 16 + l4 * 4);
            #pragma unroll
            for (int rt = 0; rt < 4; rt++) {
                float s0 = __builtin_amdgcn_sinf(fmaf(acc[rt][nt][0], K30REV, bb[0]));
                float s1 = __builtin_amdgcn_sinf(fmaf(acc[rt][nt][1], K30REV, bb[1]));
                float s2 = __builtin_amdgcn_sinf(fmaf(acc[rt][nt][2], K30REV, bb[2]));
                float s3 = __builtin_amdgcn_sinf(fmaf(acc[rt][nt][3], K30REV, bb[3]));
                *(uint2*)(Abuf + wr * 16384 + rt * 4096 + woff[nt]) = make_uint2(pk2(s0, s1), pk2(s2, s3));
            }
        }
        __syncthreads();   // writes visible before next layer reads
    }

    // ---- final layer (unswapped): af=A rows (fragment layout!), bf=W4 padded ----
    {
        const short* W4p = w4pad + l15 * 128 + l4 * 8;
        f32x4 a4[2];
        a4[0] = zero4;
        a4[1] = zero4;
        #pragma unroll
        for (int ks = 0; ks < 4; ks++) {
            s16x8 bw = *(const s16x8*)(W4p + ks * 32);
            #pragma unroll
            for (int q = 0; q < 2; q++) {
                // rows w*32+q*16 .. +15 -> rg = w*2+q; af = linear fragment read
                s16x8 af = *(const s16x8*)(Abuf + ((w * 2 + q) * 4 + ks) * 1024 + lane * 16);
                a4[q] = __builtin_amdgcn_mfma_f32_16x16x32_bf16(af, bw, a4[q], 0, 0, 0);
            }
        }
        if (l15 == 0) {
            float b4v = b4[0];
            #pragma unroll
            for (int q = 0; q < 2; q++) {
                int n = nbase + w * 32 + q * 16 + l4 * 4;
                const f32x4 img = *(const f32x4*)(image + n);
                f32x4 dv;
                #pragma unroll
                for (int jj = 0; jj < 4; jj++) dv[jj] = a4[q][jj] + b4v - img[jj];
                *(f32x4*)(d_nat + n) = dv;
            }
        }
    }
}

// ---------- kernel 1.5: d_nat [x][y][z] fp32 -> d_proj [z][x*128+y] bf16 ----------
__global__ void k_transpose(const float* __restrict__ d_nat, short* __restrict__ d_proj) {
    __shared__ float t[128][65];
    int x = blockIdx.x;
    for (int i = threadIdx.x; i < 8192; i += 256)
        t[i >> 6][i & 63] = d_nat[x * 8192 + i];
    __syncthreads();
    for (int i = threadIdx.x; i < 8192; i += 256) {
        int z = i >> 7, y = i & 127;
        d_proj[z * 16384 + x * 128 + y] = f2bf(t[y][z]);
    }
}

// ---------- kernel 2: NUDFT GEMM (M=64 z, N=2048 k-samples, K=16384 pixels) ----------
__launch_bounds__(256, 2)
__global__ void k_project(const short* __restrict__ d_proj, const float* __restrict__ tab,
                          float* __restrict__ part) {
    __shared__ alignas(16) float lt[4 * 32 * 132];   // 67584 B; reused as reduce buffer
    const int tid  = threadIdx.x;
    const int lane = tid & 63;
    const int w    = tid >> 6;
    const int l15  = lane & 15;
    const int l4   = lane >> 4;
    const int nblk = blockIdx.x & 63;
    const int ksp  = blockIdx.x >> 6;
    const int nbase = nblk * 32;

    for (int i = tid; i < 16384; i += 256) {
        int nl = i >> 9, r = i & 511;
        int t = r >> 7, e = r & 127;
        lt[(t * 32 + nl) * 132 + e] = tab[(nbase + nl) * 512 + r];
    }
    __syncthreads();

    f32x4 ar[4][2], ai[4][2];
    #pragma unroll
    for (int rt = 0; rt < 4; rt++)
        #pragma unroll
        for (int nt = 0; nt < 2; nt++) {
            ar[rt][nt] = (f32x4){0.f, 0.f, 0.f, 0.f};
            ai[rt][nt] = (f32x4){0.f, 0.f, 0.f, 0.f};
        }

    const int p2base = ksp * 2048 + w * 512;
    #pragma unroll 1
    for (int ks = 0; ks < 16; ks++) {
        int p2c = p2base + ks * 32;
        s16x8 afr[4];
        #pragma unroll
        for (int rt = 0; rt < 4; rt++)
            afr[rt] = *(const s16x8*)(d_proj + (rt * 16 + l15) * 16384 + p2c + l4 * 8);
        int p2 = p2c + l4 * 8;
        int x = p2 >> 7, y0 = p2 & 127;
        #pragma unroll
        for (int nt = 0; nt < 2; nt++) {
            int nl = nt * 16 + l15;
            float cA = lt[nl * 132 + x];
            float sA = lt[(32 + nl) * 132 + x];
            const float* cB = &lt[(64 + nl) * 132 + y0];
            const float* sB = &lt[(96 + nl) * 132 + y0];
            s16x8 bc, bs;
            #pragma unroll
            for (int j = 0; j < 8; j++) {
                float cb = cB[j], sb = sB[j];
                bc[j] = f2bf(cA * cb - sA * sb);
                bs[j] = f2bf(sA * cb + cA * sb);
            }
            #pragma unroll
            for (int rt = 0; rt < 4; rt++) {
                ar[rt][nt] = __builtin_amdgcn_mfma_f32_16x16x32_bf16(afr[rt], bc, ar[rt][nt], 0, 0, 0);
                ai[rt][nt] = __builtin_amdgcn_mfma_f32_16x16x32_bf16(afr[rt], bs, ai[rt][nt], 0, 0, 0);
            }
        }
    }
    __syncthreads();   // tables dead; reuse lt as reduce buffer
    float* red = lt;
    #pragma unroll
    for (int rt = 0; rt < 4; rt++)
        #pragma unroll
        for (int nt = 0; nt < 2; nt++)
            #pragma unroll
            for (int jj = 0; jj < 4; jj++) {
                int z = rt * 16 + l4 * 4 + jj;
                int q = nt * 16 + l15;
                red[(w * 64 + z) * 64 + q * 2 + 0] = ar[rt][nt][jj];
                red[(w * 64 + z) * 64 + q * 2 + 1] = ai[rt][nt][jj];
            }
    __syncthreads();
    for (int i = tid; i < 4096; i += 256) {
        int z = i >> 6, q = i & 63;
        float s = red[z * 64 + q] + red[4096 + z * 64 + q] + red[8192 + z * 64 + q] + red[12288 + z * 64 + q];
        part[((ksp * 64 + z) * 2048 + nbase + (q >> 1)) * 2 + (q & 1)] = s;
    }
}

// ---------- kernel 3: sum K-split partials, square, reduce to loss ----------
__global__ void k_loss(const float* __restrict__ part, float* __restrict__ out) {
    int g = blockIdx.x * 256 + threadIdx.x;   // 131072 (z,n) pairs
    int z = g >> 11, n = g & 2047;
    float r = 0.f, im = 0.f;
    #pragma unroll
    for (int ksp = 0; ksp < 8; ksp++) {
        const float2 v = *(const float2*)(part + ((ksp * 64 + z) * 2048 + n) * 2);
        r += v.x; im += v.y;
    }
    float val = r * r + im * im;
    #pragma unroll
    for (int o = 32; o > 0; o >>= 1) val += __shfl_xor(val, o);
    __shared__ float sred[4];
    if ((threadIdx.x & 63) == 0) sred[threadIdx.x >> 6] = val;
    __syncthreads();
    if (threadIdx.x == 0)
        atomicAdd(out, (sred[0] + sred[1] + sred[2] + sred[3]) * (0.5f / 131072.0f));
}

extern "C" void kernel_launch(void* const* d_in, const int* in_sizes, int n_in,
                              void* d_out, int out_size, void* d_ws, size_t ws_size,
                              hipStream_t stream) {
    const float* Bmat  = (const float*)d_in[1];
    const float* W0    = (const float*)d_in[2];
    const float* b0    = (const float*)d_in[3];
    const float* W1    = (const float*)d_in[4];
    const float* b1    = (const float*)d_in[5];
    const float* W2    = (const float*)d_in[6];
    const float* b2    = (const float*)d_in[7];
    const float* W3    = (const float*)d_in[8];
    const float* b3    = (const float*)d_in[9];
    const float* W4    = (const float*)d_in[10];
    const float* b4    = (const float*)d_in[11];
    const float* image = (const float*)d_in[12];
    const float* ktraj = (const float*)d_in[13];

    char* ws = (char*)d_ws;
    short* w4pad  = (short*)(ws);                  // 4 KB
    float* brev   = (float*)(ws + (8u << 10));     // 2 KB
    float* ptx    = (float*)(ws + (64u << 10));    // 32 KB
    float* pty    = (float*)(ws + (96u << 10));    // 32 KB
    float* ptz    = (float*)(ws + (128u << 10));   // 16 KB
    short* wswz   = (short*)(ws + (160u << 10));   // 128 KB (fragment-contiguous W0..W3)
    float* tab    = (float*)(ws + (1u << 20));     // 4 MB
    float* d_nat  = (float*)(ws + (5u << 20));     // 4 MB
    short* d_proj = (short*)(ws + (9u << 20));     // 2 MB
    float* part   = (float*)(ws + (11u << 20));    // 8 MB
    float* outf   = (float*)d_out;

    hipLaunchKernelGGL(k_prep,      dim3(2394), dim3(256), 0, stream,
                       ktraj, W0, W1, W2, W3, W4, b0, b1, b2, b3, Bmat,
                       tab, wswz, w4pad, brev, ptx, pty, ptz);
    hipLaunchKernelGGL(k_siren,     dim3(8192), dim3(256), 0, stream,
                       ptx, pty, ptz, brev, b4, wswz, w4pad, image, d_nat);
    hipLaunchKernelGGL(k_transpose, dim3(128),  dim3(256), 0, stream, d_nat, d_proj);
    hipLaunchKernelGGL(k_project,   dim3(512),  dim3(256), 0, stream, d_proj, tab, part);
    hipMemsetAsync(d_out, 0, sizeof(float), stream);
    hipLaunchKernelGGL(k_loss,      dim3(512),  dim3(256), 0, stream, part, outf);
}

// Round 9
// 236.369 us; speedup vs baseline: 1.2101x; 1.0508x over previous
//
#include <hip/hip_runtime.h>
#include <hip/hip_bf16.h>

#define K30REV 4.77464829275686f   /* 30/(2*pi) */

typedef __attribute__((ext_vector_type(4))) float f32x4;
typedef __attribute__((ext_vector_type(8))) short s16x8;

__device__ __forceinline__ short f2bf(float f) {
    union { float f; unsigned u; } a; a.f = f;
    unsigned r = a.u + 0x7fffu + ((a.u >> 16) & 1u);
    return (short)(r >> 16);
}

__device__ __forceinline__ unsigned pk2(float a, float b) {
    union { __hip_bfloat162 h; unsigned u; } cv;
    cv.h = __float22bfloat162_rn(make_float2(a, b));
    return cv.u;
}

// sigma-permutation: MFMA D-slot (nt, q) -> original neuron index.
// Chosen so layer L's D registers ARE layer L+1's B-fragments (consumer cols natural).
__device__ __forceinline__ int sigmaP(int nt, int q) {
    return (nt >> 1) * 32 + (q >> 2) * 8 + (nt & 1) * 4 + (q & 3);
}

// ---------- merged prep ----------
// [0,524288): radial tables tab[n][{cosA,sinA,cosB,sinB}][128]
// [+65536): Wswz — hidden weights, fragment-contiguous AND row-permuted by sigmaP:
//   wswz[layer*16384 + nt*2048 + ks*512 + lane*8 + j]
//     = W_layer[sigmaP(nt, lane&15)][ks*32 + (lane>>4)*8 + j]
// [+2048): W4 zero-padded [16][128] ; [+512): brev = bias[sigmaP]*K30REV ; then pt tables
__global__ void k_prep(const float* __restrict__ ktraj,
                       const float* __restrict__ W0, const float* __restrict__ W1,
                       const float* __restrict__ W2, const float* __restrict__ W3,
                       const float* __restrict__ W4,
                       const float* __restrict__ b0, const float* __restrict__ b1,
                       const float* __restrict__ b2, const float* __restrict__ b3,
                       const float* __restrict__ Bmat,
                       float* __restrict__ tab, short* __restrict__ wswz,
                       short* __restrict__ w4pad, float* __restrict__ brev,
                       float* __restrict__ ptx, float* __restrict__ pty,
                       float* __restrict__ ptz) {
    int i = blockIdx.x * 256 + threadIdx.x;
    if (i < 524288) {
        int n = i >> 8, s = i & 255;
        if (s < 128) {
            float a = ktraj[n] * (float)s;
            tab[n * 512 + s]       = __cosf(a);
            tab[n * 512 + 128 + s] = __sinf(a);
        } else {
            int y = s - 128;
            float a = ktraj[2048 + n] * (float)y;
            tab[n * 512 + 256 + y] = __cosf(a);
            tab[n * 512 + 384 + y] = __sinf(a);
        }
        return;
    }
    i -= 524288;
    if (i < 65536) {
        int layer = i >> 14, q14 = i & 16383;
        int nt = q14 >> 11, ks = (q14 >> 9) & 3;
        int ln = (q14 >> 3) & 63, j = i & 7;
        int orow = sigmaP(nt, ln & 15);
        int ocol = ks * 32 + (ln >> 4) * 8 + j;
        const float* src = (layer == 0) ? W0 : (layer == 1) ? W1 : (layer == 2) ? W2 : W3;
        wswz[i] = f2bf(src[orow * 128 + ocol]);
        return;
    }
    i -= 65536;
    if (i < 2048) {
        int row = i >> 7, col = i & 127;
        w4pad[i] = f2bf(row == 0 ? W4[col] : 0.0f);
        return;
    }
    i -= 2048;
    if (i < 512) {
        int l = i >> 7, r = i & 127;
        int orow = sigmaP(r >> 4, r & 15);
        const float* src = (l == 0) ? b0 : (l == 1) ? b1 : (l == 2) ? b2 : b3;
        brev[i] = src[orow] * K30REV;
        return;
    }
    i -= 512;
    if (i < 8192) {             // ptx
        int x = i >> 6, e = i & 63;
        ptx[i] = ((x + 0.5f) * (1.0f / 128.0f)) * Bmat[e * 3 + 0];
        return;
    }
    i -= 8192;
    if (i < 8192) {             // pty
        int y = i >> 6, e = i & 63;
        pty[i] = ((y + 0.5f) * (1.0f / 128.0f)) * Bmat[e * 3 + 1];
        return;
    }
    i -= 8192;
    if (i < 4096) {             // ptz
        int z = i >> 6, e = i & 63;
        ptz[i] = ((z + 0.5f) * (1.0f / 64.0f)) * Bmat[e * 3 + 2];
    }
}

// ---------- kernel 1: fully register-resident SIREN (no LDS, no barriers) ----------
// Each wave owns 64 points (4 row-tiles of 16). Activations live ONLY in registers:
// frag[rt][ks] (4 u32 = 8 bf16) is simultaneously the MFMA D-derived output of layer L
// (via sigmaP weight-row permutation) and the B-operand fragment of layer L+1.
// Per layer: 32 af loads (L1-hot, 1KB linear each) + 128 MFMA + 128 sin + 64 pk2.
// acc 128 f32 (AGPR) + frag 64 u32 + temps ~ 230 regs -> 2 waves/SIMD.
__launch_bounds__(256, 2)
__global__ void k_siren(const float* __restrict__ ptx, const float* __restrict__ pty,
                        const float* __restrict__ ptz,
                        const float* __restrict__ brev,
                        const float* __restrict__ b4,
                        const short* __restrict__ wswz,
                        const short* __restrict__ w4pad,
                        const float* __restrict__ image,
                        float* __restrict__ d_nat) {
    const int tid  = threadIdx.x;
    const int lane = tid & 63;
    const int w    = tid >> 6;
    const int l15  = lane & 15;
    const int l4   = lane >> 4;
    const int n0   = (blockIdx.x * 4 + w) * 64;   // wave's 64 consecutive points
    const f32x4 zero4 = (f32x4){0.f, 0.f, 0.f, 0.f};

    union F { unsigned u[4]; s16x8 v; };
    unsigned frag[4][4][4];   // [rt][ks][w]: bf16 pair (j=2w, 2w+1), k = ks*32 + l4*8 + j

    // ---- encode directly into fragments (natural k order) ----
    {
        int x = n0 >> 13, y = (n0 >> 6) & 127;    // constant across the wave's 64 points
        int e0 = l4 * 8;
        const float* px = ptx + x * 64 + e0;
        const float* py = pty + y * 64 + e0;
        f32x4 xa = *(const f32x4*)(px),      xb = *(const f32x4*)(px + 4);
        f32x4 xc = *(const f32x4*)(px + 32), xd = *(const f32x4*)(px + 36);
        f32x4 ya = *(const f32x4*)(py),      yb = *(const f32x4*)(py + 4);
        f32x4 yc = *(const f32x4*)(py + 32), yd = *(const f32x4*)(py + 36);
        float pxy[16];
        #pragma unroll
        for (int j = 0; j < 4; j++) {
            pxy[j]      = xa[j] + ya[j];
            pxy[4 + j]  = xb[j] + yb[j];
            pxy[8 + j]  = xc[j] + yc[j];
            pxy[12 + j] = xd[j] + yd[j];
        }
        #pragma unroll
        for (int rt = 0; rt < 4; rt++) {
            const float* pz = ptz + (rt * 16 + l15) * 64 + e0;
            f32x4 za = *(const f32x4*)(pz),      zb = *(const f32x4*)(pz + 4);
            f32x4 zc = *(const f32x4*)(pz + 32), zd = *(const f32x4*)(pz + 36);
            float s0[8], c0[8], s1[8], c1[8];
            #pragma unroll
            for (int j = 0; j < 4; j++) {
                float p0a = pxy[j] + za[j],      p0b = pxy[4 + j] + zb[j];
                float p1a = pxy[8 + j] + zc[j],  p1b = pxy[12 + j] + zd[j];
                s0[j]   = __builtin_amdgcn_sinf(p0a);  c0[j]   = __builtin_amdgcn_cosf(p0a);
                s0[4+j] = __builtin_amdgcn_sinf(p0b);  c0[4+j] = __builtin_amdgcn_cosf(p0b);
                s1[j]   = __builtin_amdgcn_sinf(p1a);  c1[j]   = __builtin_amdgcn_cosf(p1a);
                s1[4+j] = __builtin_amdgcn_sinf(p1b);  c1[4+j] = __builtin_amdgcn_cosf(p1b);
            }
            #pragma unroll
            for (int wq = 0; wq < 4; wq++) {
                frag[rt][0][wq] = pk2(s0[2 * wq], s0[2 * wq + 1]);   // k = e
                frag[rt][1][wq] = pk2(s1[2 * wq], s1[2 * wq + 1]);   // k = 32+e
                frag[rt][2][wq] = pk2(c0[2 * wq], c0[2 * wq + 1]);   // k = 64+e
                frag[rt][3][wq] = pk2(c1[2 * wq], c1[2 * wq + 1]);   // k = 96+e
            }
        }
    }

    // ---- 4 hidden layers, fully in-register ----
    #pragma unroll 1
    for (int layer = 0; layer < 4; layer++) {
        const short* W = wswz + layer * 16384 + lane * 8;
        const float* br = brev + layer * 128 + l4 * 4;
        f32x4 acc[4][8];

        #pragma unroll
        for (int ks = 0; ks < 4; ks++) {
            #pragma unroll
            for (int nt = 0; nt < 8; nt++) {
                s16x8 af = *(const s16x8*)(W + nt * 2048 + ks * 512);
                #pragma unroll
                for (int rt = 0; rt < 4; rt++) {
                    F bf; bf.u[0] = frag[rt][ks][0]; bf.u[1] = frag[rt][ks][1];
                          bf.u[2] = frag[rt][ks][2]; bf.u[3] = frag[rt][ks][3];
                    acc[rt][nt] = __builtin_amdgcn_mfma_f32_16x16x32_bf16(
                        af, bf.v, (ks == 0) ? zero4 : acc[rt][nt], 0, 0, 0);
                }
            }
        }
        // activation: frag'[rt][ks] = {pk2 of sin(acc[rt][2ks])..., pk2 of sin(acc[rt][2ks+1])...}
        #pragma unroll
        for (int ks = 0; ks < 4; ks++) {
            f32x4 bbA = *(const f32x4*)(br + (2 * ks) * 16);
            f32x4 bbB = *(const f32x4*)(br + (2 * ks + 1) * 16);
            #pragma unroll
            for (int rt = 0; rt < 4; rt++) {
                float a0 = __builtin_amdgcn_sinf(fmaf(acc[rt][2 * ks][0],     K30REV, bbA[0]));
                float a1 = __builtin_amdgcn_sinf(fmaf(acc[rt][2 * ks][1],     K30REV, bbA[1]));
                float a2 = __builtin_amdgcn_sinf(fmaf(acc[rt][2 * ks][2],     K30REV, bbA[2]));
                float a3 = __builtin_amdgcn_sinf(fmaf(acc[rt][2 * ks][3],     K30REV, bbA[3]));
                float b0 = __builtin_amdgcn_sinf(fmaf(acc[rt][2 * ks + 1][0], K30REV, bbB[0]));
                float b1 = __builtin_amdgcn_sinf(fmaf(acc[rt][2 * ks + 1][1], K30REV, bbB[1]));
                float b2 = __builtin_amdgcn_sinf(fmaf(acc[rt][2 * ks + 1][2], K30REV, bbB[2]));
                float b3 = __builtin_amdgcn_sinf(fmaf(acc[rt][2 * ks + 1][3], K30REV, bbB[3]));
                frag[rt][ks][0] = pk2(a0, a1);
                frag[rt][ks][1] = pk2(a2, a3);
                frag[rt][ks][2] = pk2(b0, b1);
                frag[rt][ks][3] = pk2(b2, b3);
            }
        }
    }

    // ---- final layer: A-operand = frags (points x k), B = W4 padded ----
    {
        const short* W4p = w4pad + l15 * 128 + l4 * 8;
        f32x4 a4[4] = {zero4, zero4, zero4, zero4};
        #pragma unroll
        for (int ks = 0; ks < 4; ks++) {
            s16x8 bw = *(const s16x8*)(W4p + ks * 32);
            #pragma unroll
            for (int rt = 0; rt < 4; rt++) {
                F bf; bf.u[0] = frag[rt][ks][0]; bf.u[1] = frag[rt][ks][1];
                      bf.u[2] = frag[rt][ks][2]; bf.u[3] = frag[rt][ks][3];
                a4[rt] = __builtin_amdgcn_mfma_f32_16x16x32_bf16(bf.v, bw, a4[rt], 0, 0, 0);
            }
        }
        if (l15 == 0) {   // lane holds output col 0 for points rt*16 + l4*4 + jj
            float b4v = b4[0];
            #pragma unroll
            for (int rt = 0; rt < 4; rt++) {
                int n = n0 + rt * 16 + l4 * 4;
                const f32x4 img = *(const f32x4*)(image + n);
                f32x4 dv;
                #pragma unroll
                for (int jj = 0; jj < 4; jj++) dv[jj] = a4[rt][jj] + b4v - img[jj];
                *(f32x4*)(d_nat + n) = dv;
            }
        }
    }
}

// ---------- kernel 1.5: d_nat [x][y][z] fp32 -> d_proj [z][x*128+y] bf16 ----------
__global__ void k_transpose(const float* __restrict__ d_nat, short* __restrict__ d_proj) {
    __shared__ float t[128][65];
    int x = blockIdx.x;
    for (int i = threadIdx.x; i < 8192; i += 256)
        t[i >> 6][i & 63] = d_nat[x * 8192 + i];
    __syncthreads();
    for (int i = threadIdx.x; i < 8192; i += 256) {
        int z = i >> 7, y = i & 127;
        d_proj[z * 16384 + x * 128 + y] = f2bf(t[y][z]);
    }
}

// ---------- kernel 2: NUDFT GEMM (M=64 z, N=2048 k-samples, K=16384 pixels) ----------
__launch_bounds__(256, 2)
__global__ void k_project(const short* __restrict__ d_proj, const float* __restrict__ tab,
                          float* __restrict__ part) {
    __shared__ alignas(16) float lt[4 * 32 * 132];   // 67584 B; reused as reduce buffer
    const int tid  = threadIdx.x;
    const int lane = tid & 63;
    const int w    = tid >> 6;
    const int l15  = lane & 15;
    const int l4   = lane >> 4;
    const int nblk = blockIdx.x & 63;
    const int ksp  = blockIdx.x >> 6;
    const int nbase = nblk * 32;

    for (int i = tid; i < 16384; i += 256) {
        int nl = i >> 9, r = i & 511;
        int t = r >> 7, e = r & 127;
        lt[(t * 32 + nl) * 132 + e] = tab[(nbase + nl) * 512 + r];
    }
    __syncthreads();

    f32x4 ar[4][2], ai[4][2];
    #pragma unroll
    for (int rt = 0; rt < 4; rt++)
        #pragma unroll
        for (int nt = 0; nt < 2; nt++) {
            ar[rt][nt] = (f32x4){0.f, 0.f, 0.f, 0.f};
            ai[rt][nt] = (f32x4){0.f, 0.f, 0.f, 0.f};
        }

    const int p2base = ksp * 2048 + w * 512;
    #pragma unroll 1
    for (int ks = 0; ks < 16; ks++) {
        int p2c = p2base + ks * 32;
        s16x8 afr[4];
        #pragma unroll
        for (int rt = 0; rt < 4; rt++)
            afr[rt] = *(const s16x8*)(d_proj + (rt * 16 + l15) * 16384 + p2c + l4 * 8);
        int p2 = p2c + l4 * 8;
        int x = p2 >> 7, y0 = p2 & 127;
        #pragma unroll
        for (int nt = 0; nt < 2; nt++) {
            int nl = nt * 16 + l15;
            float cA = lt[nl * 132 + x];
            float sA = lt[(32 + nl) * 132 + x];
            const float* cB = &lt[(64 + nl) * 132 + y0];
            const float* sB = &lt[(96 + nl) * 132 + y0];
            s16x8 bc, bs;
            #pragma unroll
            for (int j = 0; j < 8; j++) {
                float cb = cB[j], sb = sB[j];
                bc[j] = f2bf(cA * cb - sA * sb);
                bs[j] = f2bf(sA * cb + cA * sb);
            }
            #pragma unroll
            for (int rt = 0; rt < 4; rt++) {
                ar[rt][nt] = __builtin_amdgcn_mfma_f32_16x16x32_bf16(afr[rt], bc, ar[rt][nt], 0, 0, 0);
                ai[rt][nt] = __builtin_amdgcn_mfma_f32_16x16x32_bf16(afr[rt], bs, ai[rt][nt], 0, 0, 0);
            }
        }
    }
    __syncthreads();   // tables dead; reuse lt as reduce buffer
    float* red = lt;
    #pragma unroll
    for (int rt = 0; rt < 4; rt++)
        #pragma unroll
        for (int nt = 0; nt < 2; nt++)
            #pragma unroll
            for (int jj = 0; jj < 4; jj++) {
                int z = rt * 16 + l4 * 4 + jj;
                int q = nt * 16 + l15;
                red[(w * 64 + z) * 64 + q * 2 + 0] = ar[rt][nt][jj];
                red[(w * 64 + z) * 64 + q * 2 + 1] = ai[rt][nt][jj];
            }
    __syncthreads();
    for (int i = tid; i < 4096; i += 256) {
        int z = i >> 6, q = i & 63;
        float s = red[z * 64 + q] + red[4096 + z * 64 + q] + red[8192 + z * 64 + q] + red[12288 + z * 64 + q];
        part[((ksp * 64 + z) * 2048 + nbase + (q >> 1)) * 2 + (q & 1)] = s;
    }
}

// ---------- kernel 3: sum K-split partials, square, reduce to loss ----------
__global__ void k_loss(const float* __restrict__ part, float* __restrict__ out) {
    int g = blockIdx.x * 256 + threadIdx.x;   // 131072 (z,n) pairs
    int z = g >> 11, n = g & 2047;
    float r = 0.f, im = 0.f;
    #pragma unroll
    for (int ksp = 0; ksp < 8; ksp++) {
        const float2 v = *(const float2*)(part + ((ksp * 64 + z) * 2048 + n) * 2);
        r += v.x; im += v.y;
    }
    float val = r * r + im * im;
    #pragma unroll
    for (int o = 32; o > 0; o >>= 1) val += __shfl_xor(val, o);
    __shared__ float sred[4];
    if ((threadIdx.x & 63) == 0) sred[threadIdx.x >> 6] = val;
    __syncthreads();
    if (threadIdx.x == 0)
        atomicAdd(out, (sred[0] + sred[1] + sred[2] + sred[3]) * (0.5f / 131072.0f));
}

extern "C" void kernel_launch(void* const* d_in, const int* in_sizes, int n_in,
                              void* d_out, int out_size, void* d_ws, size_t ws_size,
                              hipStream_t stream) {
    const float* Bmat  = (const float*)d_in[1];
    const float* W0    = (const float*)d_in[2];
    const float* b0    = (const float*)d_in[3];
    const float* W1    = (const float*)d_in[4];
    const float* b1    = (const float*)d_in[5];
    const float* W2    = (const float*)d_in[6];
    const float* b2    = (const float*)d_in[7];
    const float* W3    = (const float*)d_in[8];
    const float* b3    = (const float*)d_in[9];
    const float* W4    = (const float*)d_in[10];
    const float* b4    = (const float*)d_in[11];
    const float* image = (const float*)d_in[12];
    const float* ktraj = (const float*)d_in[13];

    char* ws = (char*)d_ws;
    short* w4pad  = (short*)(ws);                  // 4 KB
    float* brev   = (float*)(ws + (8u << 10));     // 2 KB (sigma-permuted, prescaled)
    float* ptx    = (float*)(ws + (64u << 10));    // 32 KB
    float* pty    = (float*)(ws + (96u << 10));    // 32 KB
    float* ptz    = (float*)(ws + (128u << 10));   // 16 KB
    short* wswz   = (short*)(ws + (160u << 10));   // 128 KB (sigma-permuted fragment W0..W3)
    float* tab    = (float*)(ws + (1u << 20));     // 4 MB
    float* d_nat  = (float*)(ws + (5u << 20));     // 4 MB
    short* d_proj = (short*)(ws + (9u << 20));     // 2 MB
    float* part   = (float*)(ws + (11u << 20));    // 8 MB
    float* outf   = (float*)d_out;

    hipLaunchKernelGGL(k_prep,      dim3(2394), dim3(256), 0, stream,
                       ktraj, W0, W1, W2, W3, W4, b0, b1, b2, b3, Bmat,
                       tab, wswz, w4pad, brev, ptx, pty, ptz);
    hipLaunchKernelGGL(k_siren,     dim3(4096), dim3(256), 0, stream,
                       ptx, pty, ptz, brev, b4, wswz, w4pad, image, d_nat);
    hipLaunchKernelGGL(k_transpose, dim3(128),  dim3(256), 0, stream, d_nat, d_proj);
    hipLaunchKernelGGL(k_project,   dim3(512),  dim3(256), 0, stream, d_proj, tab, part);
    hipMemsetAsync(d_out, 0, sizeof(float), stream);
    hipLaunchKernelGGL(k_loss,      dim3(512),  dim3(256), 0, stream, part, outf);
}